// Round 18
// baseline (277.623 us; speedup 1.0000x reference)
//
#include <hip/hip_runtime.h>
#include <hip/hip_bf16.h>

// Biattention: x:[8,2048,1024] f32, mask:[8,2048] i32
// out = concat([x, c, x+c, x-c, x*c], -1) where c = softmax(mask(x x^T)) x
//
// R18 = R17 with compile fix (nontemporal store needs ext_vector type, not
// HIP_vector_type ushort4). MASK COMPACTION: masked keys have P == 0 exactly
// (exp(-inf)); dropping exact zeros from PV is exact. k_scan builds
// cidx/orig/Nb; softmax writes P compacted (+pad0); k_gatherT builds
// compact-transposed xT_c; k_context loops nt = ceil(Nb/64) (>=2).
// Output bitwise identical to R16 (absmax must stay exactly 0.21875).

typedef __attribute__((ext_vector_type(8))) _Float16 half8;
typedef __attribute__((ext_vector_type(8))) unsigned short ushort8;
typedef __attribute__((ext_vector_type(4))) unsigned short us4;
typedef __attribute__((ext_vector_type(4))) float f32x4;

#define SEQ 2048
#define DIM 1024
#define NBATCH 8
#define BK 32

__device__ __forceinline__ unsigned short f2h(float f) {
  union { _Float16 h; unsigned short u; } cv;
  cv.h = (_Float16)f;
  return cv.u;
}
__device__ __forceinline__ float h2f(unsigned short u) {
  union { _Float16 h; unsigned short u; } cv;
  cv.u = u;
  return (float)cv.h;
}

__device__ __forceinline__ void load16(const void* g, void* l) {
  __builtin_amdgcn_global_load_lds(
      (const __attribute__((address_space(1))) unsigned int*)g,
      (__attribute__((address_space(3))) unsigned int*)l, 16, 0, 0);
}

// ---------------- K1: convert (fp16 h only; transpose moved to gatherT) ----------------
__global__ __launch_bounds__(256) void k_prep(
    const float* __restrict__ x, unsigned short* __restrict__ xh) {
  long i = ((long)blockIdx.x * 256 + threadIdx.x) * 8;
  float4 a = *(const float4*)(x + i);
  float4 c = *(const float4*)(x + i + 4);
  ushort8 o;
  o[0] = f2h(a.x); o[1] = f2h(a.y); o[2] = f2h(a.z); o[3] = f2h(a.w);
  o[4] = f2h(c.x); o[5] = f2h(c.y); o[6] = f2h(c.z); o[7] = f2h(c.w);
  *(ushort8*)(xh + i) = o;
}

// ---------------- K1b: mask scan (1 wave per batch) ----------------
__global__ __launch_bounds__(64) void k_scan(
    const int* __restrict__ mask, int* __restrict__ cidx,
    int* __restrict__ orig, int* __restrict__ meta) {
  int b = blockIdx.x, lane = threadIdx.x;
  const int* mp = mask + b * SEQ;
  int loc[32];
  int cnt = 0;
#pragma unroll
  for (int i = 0; i < 8; ++i) {
    int4 v = *(const int4*)(mp + lane * 32 + i * 4);
    loc[i * 4 + 0] = v.x; loc[i * 4 + 1] = v.y;
    loc[i * 4 + 2] = v.z; loc[i * 4 + 3] = v.w;
    cnt += (v.x != 0) + (v.y != 0) + (v.z != 0) + (v.w != 0);
  }
  int incl = cnt;
#pragma unroll
  for (int off = 1; off < 64; off <<= 1) {
    int t = __shfl_up(incl, off, 64);
    if (lane >= off) incl += t;
  }
  int run = incl - cnt;
  int* cb = cidx + b * SEQ;
  int* ob = orig + b * SEQ;
#pragma unroll
  for (int i = 0; i < 32; ++i) {
    int col = lane * 32 + i;
    cb[col] = run;
    if (loc[i]) { ob[run] = col; ++run; }
  }
  if (lane == 63) {
    int nb = incl;
    int nt = (nb + 63) >> 6;
    if (nt < 2) nt = 2;
    meta[b] = nb;
    meta[8 + b] = nt;
  }
}

// ---------------- K1c: gather-transpose (xT_c[d][j] = xh[orig[j]][d], pad 0) ----------------
__global__ __launch_bounds__(256) void k_gatherT(
    const unsigned short* __restrict__ xh, const int* __restrict__ orig,
    const int* __restrict__ meta, unsigned short* __restrict__ xTc) {
  int b = blockIdx.z;
  int j0 = blockIdx.x * 64;
  int d0 = blockIdx.y * 64;
  int nb = meta[b];
  int npad = meta[8 + b] * 64;
  if (j0 >= npad) return;
  __shared__ unsigned short t[64][72];
  int r = threadIdx.x >> 2;         // 0..63
  int c0 = (threadIdx.x & 3) * 16;  // 0,16,32,48
  int j = j0 + r;
  ushort8 v0 = {0, 0, 0, 0, 0, 0, 0, 0};
  ushort8 v1 = {0, 0, 0, 0, 0, 0, 0, 0};
  if (j < nb) {
    int src = orig[b * SEQ + j];
    const unsigned short* sp = xh + ((long)b * SEQ + src) * DIM + d0 + c0;
    v0 = *(const ushort8*)sp;
    v1 = *(const ushort8*)(sp + 8);
  }
  *(ushort8*)&t[r][c0] = v0;
  *(ushort8*)&t[r][c0 + 8] = v1;
  __syncthreads();
  ushort8 w0, w1;
#pragma unroll
  for (int k = 0; k < 8; ++k) { w0[k] = t[c0 + k][r]; w1[k] = t[c0 + 8 + k][r]; }
  unsigned short* dp = xTc + ((long)b * DIM + d0 + r) * SEQ + j0 + c0;
  *(ushort8*)dp = w0;
  *(ushort8*)(dp + 8) = w1;
}

// shared compute macro (R5-exact structure, f16 MFMA) — used by k_scores
#define COMPUTE_TILE(ARR_A, ARR_B, BUF)                                     \
  {                                                                         \
    half8 af[4], bg[4];                                                     \
    _Pragma("unroll") for (int m = 0; m < 4; ++m) {                         \
      int R = wr * 64 + m * 16 + l15;                                       \
      af[m] = *(const half8*)&ARR_A[BUF][R * BK + ((lhi ^ ((R >> 1) & 3)) * 8)]; \
    }                                                                       \
    _Pragma("unroll") for (int n = 0; n < 4; ++n) {                         \
      int R = wc * 64 + n * 16 + l15;                                       \
      bg[n] = *(const half8*)&ARR_B[BUF][R * BK + ((lhi ^ ((R >> 1) & 3)) * 8)]; \
    }                                                                       \
    _Pragma("unroll") for (int m = 0; m < 4; ++m)                           \
      _Pragma("unroll") for (int n = 0; n < 4; ++n)                         \
        acc[m][n] = __builtin_amdgcn_mfma_f32_16x16x32_f16(af[m], bg[n], acc[m][n], 0, 0, 0); \
  }

// ---------------- K2: scores GEMM (128^2, single-pass h h^T, d3) ----------------
#define NT_SC 32
__global__ __launch_bounds__(256) void k_scores(
    const unsigned short* __restrict__ xh, unsigned short* __restrict__ S) {
  __shared__ unsigned short As[3][128 * BK];
  __shared__ unsigned short Bs[3][128 * BK];
  int p = blockIdx.x + 136 * blockIdx.z;   // 0..1087
  int b = p & 7;                            // one batch per XCD (T1)
  int t = p >> 3;                           // tri-index 0..135
  int bm = 0, rem = 16;
  while (t >= rem) { t -= rem; ++bm; --rem; }
  int bn = bm + t;
  int m0 = bm * 128;
  int n0 = bn * 128;
  const unsigned short* xh_b = xh + (long)b * SEQ * DIM;
  unsigned short* S_b = S + (long)b * SEQ * SEQ;

  int tid = threadIdx.x;
  int w = tid >> 6, lane = tid & 63;
  int wr = w >> 1, wc = w & 1;
  int l15 = lane & 15, lhi = lane >> 4;

  int cbase0 = w * 64, cbase1 = 256 + w * 64;
  int c0 = cbase0 + lane, c1 = cbase1 + lane;
  int row0 = c0 >> 2, row1 = c1 >> 2;
  long aoff0 = (long)(m0 + row0) * DIM + ((c0 & 3) ^ ((row0 >> 1) & 3)) * 8;
  long aoff1 = (long)(m0 + row1) * DIM + ((c1 & 3) ^ ((row1 >> 1) & 3)) * 8;
  long boff0 = (long)(n0 + row0) * DIM + ((c0 & 3) ^ ((row0 >> 1) & 3)) * 8;
  long boff1 = (long)(n0 + row1) * DIM + ((c1 & 3) ^ ((row1 >> 1) & 3)) * 8;

#define STAGE_SC(KT, BUF)                                                   \
  {                                                                         \
    int kk_ = (KT) * BK;                                                    \
    load16(xh_b + aoff0 + kk_, &As[BUF][cbase0 * 8]);                       \
    load16(xh_b + aoff1 + kk_, &As[BUF][cbase1 * 8]);                       \
    load16(xh_b + boff0 + kk_, &Bs[BUF][cbase0 * 8]);                       \
    load16(xh_b + boff1 + kk_, &Bs[BUF][cbase1 * 8]);                       \
  }

  f32x4 acc[4][4];
#pragma unroll
  for (int m = 0; m < 4; ++m)
#pragma unroll
    for (int n = 0; n < 4; ++n)
#pragma unroll
      for (int j = 0; j < 4; ++j) acc[m][n][j] = 0.0f;

  STAGE_SC(0, 0);
  STAGE_SC(1, 1);
  STAGE_SC(2, 2);
  int cur = 0;
  for (int kt = 0; kt < NT_SC - 2; ++kt) {
    asm volatile("s_waitcnt vmcnt(8)" ::: "memory");
    __builtin_amdgcn_s_barrier();
    __builtin_amdgcn_sched_barrier(0);
    COMPUTE_TILE(As, Bs, cur);
    __builtin_amdgcn_sched_barrier(0);
    __builtin_amdgcn_s_barrier();
    if (kt + 3 < NT_SC) STAGE_SC(kt + 3, cur);
    cur = (cur == 2) ? 0 : cur + 1;
  }
  asm volatile("s_waitcnt vmcnt(4)" ::: "memory");
  __builtin_amdgcn_s_barrier();
  COMPUTE_TILE(As, Bs, (NT_SC - 2) % 3);
  asm volatile("s_waitcnt vmcnt(0)" ::: "memory");
  __builtin_amdgcn_s_barrier();
  COMPUTE_TILE(As, Bs, (NT_SC - 1) % 3);

  // S writes nontemporal (protect L2-resident xh panels)
#pragma unroll
  for (int m = 0; m < 4; ++m)
#pragma unroll
    for (int n = 0; n < 4; ++n)
#pragma unroll
      for (int j = 0; j < 4; ++j) {
        int r = m0 + wr * 64 + m * 16 + lhi * 4 + j;
        int c = n0 + wc * 64 + n * 16 + l15;
        __builtin_nontemporal_store(f2h(acc[m][n][j]), &S_b[(long)r * SEQ + c]);
      }
  if (bm != bn) {
#pragma unroll
    for (int m = 0; m < 4; ++m)
#pragma unroll
      for (int n = 0; n < 4; ++n) {
        int r0 = m0 + wr * 64 + m * 16 + lhi * 4;
        int c = n0 + wc * 64 + n * 16 + l15;
        us4 pk = {f2h(acc[m][n][0]), f2h(acc[m][n][1]),
                  f2h(acc[m][n][2]), f2h(acc[m][n][3])};
        __builtin_nontemporal_store(pk, (us4*)&S_b[(long)c * SEQ + r0]);
      }
  }
}

// ---------------- K3: masked softmax -> COMPACT P (fp16), wave per row ----------------
__global__ __launch_bounds__(256) void k_softmax(
    const unsigned short* __restrict__ S, const int* __restrict__ mask,
    const int* __restrict__ cidx, const int* __restrict__ meta,
    unsigned short* __restrict__ P) {
  int w = threadIdx.x >> 6, lane = threadIdx.x & 63;
  long row = (long)blockIdx.x * 4 + w;
  int b = (int)(row >> 11);
  const unsigned short* Sp = S + row * SEQ;
  const int* mp = mask + b * SEQ;
  unsigned short* Pp = P + row * SEQ;

  float sv[32];
  float mx = -__builtin_inff();
#pragma unroll
  for (int ci = 0; ci < 4; ++ci) {
    int col = ci * 512 + lane * 8;
    ushort8 v = *(const ushort8*)(Sp + col);
    int4 ma = *(const int4*)(mp + col);
    int4 mb = *(const int4*)(mp + col + 4);
    int mk[8] = {ma.x, ma.y, ma.z, ma.w, mb.x, mb.y, mb.z, mb.w};
#pragma unroll
    for (int j = 0; j < 8; ++j) {
      float s = mk[j] ? h2f(v[j]) : -__builtin_inff();
      sv[ci * 8 + j] = s;
      mx = fmaxf(mx, s);
    }
  }
#pragma unroll
  for (int off = 32; off; off >>= 1) mx = fmaxf(mx, __shfl_xor(mx, off));
  float pv[32];
  float sum = 0.0f;
#pragma unroll
  for (int i = 0; i < 32; ++i) {
    pv[i] = expf(sv[i] - mx);
    sum += pv[i];
  }
#pragma unroll
  for (int off = 32; off; off >>= 1) sum += __shfl_xor(sum, off);
  float inv = 1.0f / sum;
  // compact write: unmasked cols -> cidx positions (monotonic)
  const int* cb = cidx + b * SEQ;
#pragma unroll
  for (int ci = 0; ci < 4; ++ci) {
    int col = ci * 512 + lane * 8;
    int4 ca = *(const int4*)(cb + col);
    int4 c2 = *(const int4*)(cb + col + 4);
    int cd[8] = {ca.x, ca.y, ca.z, ca.w, c2.x, c2.y, c2.z, c2.w};
#pragma unroll
    for (int j = 0; j < 8; ++j)
      if (sv[ci * 8 + j] > -1e30f) Pp[cd[j]] = f2h(pv[ci * 8 + j] * inv);
  }
  // zero-pad to tile boundary
  int nb = meta[b];
  int npad = meta[8 + b] * 64;
  for (int j = nb + lane; j < npad; j += 64) Pp[j] = 0;
}

// ---------------- K4: context GEMM 256^2 BK=64, 2 phases/tile, dynamic nt ----------------
__global__ __launch_bounds__(512, 2) void k_context(
    const unsigned short* __restrict__ P, const unsigned short* __restrict__ xT,
    const float* __restrict__ x, const int* __restrict__ meta,
    float* __restrict__ out) {
  __shared__ unsigned short As[2 * 16384];  // 64 KB
  __shared__ unsigned short Bs[2 * 16384];  // 64 KB
  int p = blockIdx.x;            // 0..255
  int b = p & 7;                 // one batch per XCD (T1)
  int q = p >> 3;                // 0..31
  int n0 = (q & 3) * 256;        // d cols
  int m0 = (q >> 2) * 256;       // q rows
  int nt = meta[8 + b];          // compact K tiles (>= 2)
  const unsigned short* A_b = P + (long)b * SEQ * SEQ;
  const unsigned short* B_b = xT + (long)b * DIM * SEQ;

  int tid = threadIdx.x;
  int w = tid >> 6, lane = tid & 63;
  int wr = w >> 2, wc = w & 3;          // 2M x 4N waves; per-wave 128x64
  int l15 = lane & 15, lhi = lane >> 4;

  int c0 = w * 128 + lane, c1 = w * 128 + 64 + lane;
  int R0 = c0 >> 2, R1 = c1 >> 2;
  int sw0 = ((c0 & 3) ^ ((R0 >> 1) & 3)) * 8;
  int sw1 = ((c1 & 3) ^ ((R1 >> 1) & 3)) * 8;
  const unsigned short* PA0 = A_b + (long)(m0 + R0) * SEQ + sw0;
  const unsigned short* PA1 = A_b + (long)(m0 + R1) * SEQ + sw1;
  const unsigned short* PB0 = B_b + (long)(n0 + R0) * SEQ + sw0;
  const unsigned short* PB1 = B_b + (long)(n0 + R1) * SEQ + sw1;
  int ldg0 = (w * 128) * 8;
  int ldg1 = (w * 128 + 64) * 8;

#define STG_A(KT, KK, BUF)                                              \
  {                                                                     \
    load16(PA0 + (KT) * 64 + (KK) * 32, &As[(BUF)*16384 + (KK)*8192 + ldg0]); \
    load16(PA1 + (KT) * 64 + (KK) * 32, &As[(BUF)*16384 + (KK)*8192 + ldg1]); \
  }
#define STG_B(KT, KK, BUF)                                              \
  {                                                                     \
    load16(PB0 + (KT) * 64 + (KK) * 32, &Bs[(BUF)*16384 + (KK)*8192 + ldg0]); \
    load16(PB1 + (KT) * 64 + (KK) * 32, &Bs[(BUF)*16384 + (KK)*8192 + ldg1]); \
  }

  int swr = (lhi ^ ((l15 >> 1) & 3)) * 8;
  int arow = (wr * 128 + l15) * 32;
  int brow = (wc * 64 + l15) * 32;

#define PHASE_CTX(BUF, KK, DO_STG_A, DO_STG_B, STKT, STKK, STBUF)             \
  {                                                                           \
    half8 af[8], bg[4];                                                       \
    _Pragma("unroll") for (int n = 0; n < 4; ++n)                             \
        bg[n] = *(const half8*)&Bs[(BUF)*16384 + (KK)*8192 + brow + n * 512 + swr]; \
    _Pragma("unroll") for (int m = 0; m < 8; ++m)                             \
        af[m] = *(const half8*)&As[(BUF)*16384 + (KK)*8192 + arow + m * 512 + swr]; \
    if (DO_STG_A) STG_A(STKT, STKK, STBUF);                                   \
    if (DO_STG_B) STG_B(STKT, STKK, STBUF);                                   \
    __builtin_amdgcn_s_barrier();                                             \
    asm volatile("s_waitcnt lgkmcnt(0)" ::: "memory");                        \
    __builtin_amdgcn_sched_barrier(0);                                        \
    __builtin_amdgcn_s_setprio(1);                                            \
    _Pragma("unroll") for (int m = 0; m < 8; ++m)                             \
      _Pragma("unroll") for (int n = 0; n < 4; ++n)                           \
        acc[m][n] = __builtin_amdgcn_mfma_f32_16x16x32_f16(                   \
            bg[n], af[m], acc[m][n], 0, 0, 0);                                \
    __builtin_amdgcn_s_setprio(0);                                            \
    __builtin_amdgcn_sched_barrier(0);                                        \
  }

  f32x4 acc[8][4];
#pragma unroll
  for (int m = 0; m < 8; ++m)
#pragma unroll
    for (int n = 0; n < 4; ++n)
#pragma unroll
      for (int j = 0; j < 4; ++j) acc[m][n][j] = 0.0f;

  // prologue: kt0 full (8 loads) + kt1 kk0 (4 loads); drain kt0 -> vmcnt(4)
  STG_A(0, 0, 0); STG_B(0, 0, 0);
  STG_A(0, 1, 0); STG_B(0, 1, 0);
  STG_A(1, 0, 1); STG_B(1, 0, 1);
  asm volatile("s_waitcnt vmcnt(4)" ::: "memory");
  __builtin_amdgcn_s_barrier();

  for (int kt = 0; kt < nt; ++kt) {
    int c = kt & 1, o = c ^ 1;
    int haveN1 = (kt + 1 < nt), haveN2 = (kt + 2 < nt);
    // phase A: compute kk0 of c; stage kt+1-kk1 -> o
    PHASE_CTX(c, 0, haveN1, haveN1, kt + 1, 1, o);
    __builtin_amdgcn_s_barrier();   // all waves done reading c-kk0
    // phase B: compute kk1 of c; stage kt+2-kk0 -> c (region just released)
    PHASE_CTX(c, 1, haveN2, haveN2, kt + 2, 0, c);
    if (kt < nt - 2) {
      asm volatile("s_waitcnt vmcnt(4)" ::: "memory");
    } else if (kt == nt - 2) {
      asm volatile("s_waitcnt vmcnt(0)" ::: "memory");
    }
    __builtin_amdgcn_s_barrier();
  }

  // epilogue: swapped-operand C layout -> thread holds 4 consecutive d (f32x4)
  const float* x_b = x + (long)b * SEQ * DIM;
  float* out_b = out + (long)b * SEQ * (5 * DIM);
#pragma unroll
  for (int m = 0; m < 8; ++m)
#pragma unroll
    for (int n = 0; n < 4; ++n) {
      int qi = m0 + wr * 128 + m * 16 + l15;      // col index = q
      int d = n0 + wc * 64 + n * 16 + lhi * 4;    // row index = d (4 consec)
      f32x4 c4 = acc[m][n];
      f32x4 xv = *(const f32x4*)&x_b[(long)qi * DIM + d];
      long base = (long)qi * (5 * DIM) + d;
      __builtin_nontemporal_store(xv,       (f32x4*)&out_b[base]);
      __builtin_nontemporal_store(c4,       (f32x4*)&out_b[base + DIM]);
      __builtin_nontemporal_store(xv + c4,  (f32x4*)&out_b[base + 2 * DIM]);
      __builtin_nontemporal_store(xv - c4,  (f32x4*)&out_b[base + 3 * DIM]);
      __builtin_nontemporal_store(xv * c4,  (f32x4*)&out_b[base + 4 * DIM]);
    }
}

extern "C" void kernel_launch(void* const* d_in, const int* in_sizes, int n_in,
                              void* d_out, int out_size, void* d_ws, size_t ws_size,
                              hipStream_t stream) {
  const float* x = (const float*)d_in[0];
  const int* mask = (const int*)d_in[1];
  float* out = (float*)d_out;
  char* ws = (char*)d_ws;

  const size_t HB = (size_t)NBATCH * SEQ * DIM * 2;       // 33,554,432
  const size_t PB = (size_t)NBATCH * SEQ * SEQ * 2;       // 67,108,864
  const size_t SB = (size_t)NBATCH * SEQ * SEQ * 2;
  const size_t IB = (size_t)NBATCH * SEQ * 4;             // 65,536
  unsigned short* xh  = (unsigned short*)ws;
  unsigned short* xTc = (unsigned short*)(ws + HB);
  unsigned short* Pc  = (unsigned short*)(ws + 2 * HB);
  int* cidx = (int*)(ws + 2 * HB + PB);
  int* orig = (int*)(ws + 2 * HB + PB + IB);
  int* meta = (int*)(ws + 2 * HB + PB + 2 * IB);
  size_t meta_end = 2 * HB + PB + 2 * IB + 1024;
  unsigned short* S;
  if (ws_size >= meta_end + SB) {
    S = (unsigned short*)(ws + meta_end);
  } else {
    S = (unsigned short*)d_out;  // S dead before context writes out
  }

  k_prep<<<dim3((int)((size_t)NBATCH * SEQ * DIM / (256 * 8)), 1, 1), 256, 0, stream>>>(x, xh);
  k_scan<<<dim3(NBATCH, 1, 1), 64, 0, stream>>>(mask, cidx, orig, meta);
  k_scores<<<dim3(136, 1, NBATCH), 256, 0, stream>>>(xh, S);
  k_gatherT<<<dim3(32, 16, NBATCH), 256, 0, stream>>>(xh, orig, meta, xTc);
  k_softmax<<<NBATCH * SEQ / 4, 256, 0, stream>>>(S, mask, cidx, meta, Pc);
  k_context<<<dim3(256, 1, 1), 512, 0, stream>>>(Pc, xTc, x, meta, out);
}

// Round 19
// 251.358 us; speedup vs baseline: 1.1045x; 1.1045x over previous
//
#include <hip/hip_runtime.h>
#include <hip/hip_bf16.h>

// Biattention: x:[8,2048,1024] f32, mask:[8,2048] i32
// out = concat([x, c, x+c, x-c, x*c], -1) where c = softmax(mask(x x^T)) x
//
// R19 = R16-exact revert (best measured: 250.2us, absmax 0.21875).
// R17/R18's mask compaction was bitwise-correct but net-slower (+27us:
// gatherT pass + scalar scatter softmax + NT-on-re-read-S mistake).
// Locked structure:
//  prep:    fp16 h + hT transpose                 (~28us)
//  scores:  128^2 d3 compiler-scheduled, single-pass S = h h^T, fp16 S,
//           tri-blocks + mirror write             (~60us)
//  softmax: wave/row, fp16 in/out, vectorized     (~22us)
//  context: 256^2 BK=64 8-wave 2-phase disciplined (vmcnt(4) ladder), fp16,
//           swapped-op f32x4 epilogue, NT stores  (~140us)
// T1 batch-per-XCD, T2 swizzle (verified 0 bank conflicts) throughout.

typedef __attribute__((ext_vector_type(8))) _Float16 half8;
typedef __attribute__((ext_vector_type(8))) unsigned short ushort8;
typedef __attribute__((ext_vector_type(4))) float f32x4;

#define SEQ 2048
#define DIM 1024
#define NBATCH 8
#define BK 32

__device__ __forceinline__ unsigned short f2h(float f) {
  union { _Float16 h; unsigned short u; } cv;
  cv.h = (_Float16)f;
  return cv.u;
}
__device__ __forceinline__ float h2f(unsigned short u) {
  union { _Float16 h; unsigned short u; } cv;
  cv.u = u;
  return (float)cv.h;
}

__device__ __forceinline__ void load16(const void* g, void* l) {
  __builtin_amdgcn_global_load_lds(
      (const __attribute__((address_space(1))) unsigned int*)g,
      (__attribute__((address_space(3))) unsigned int*)l, 16, 0, 0);
}

// ---------------- K1: convert + transpose (fp16; emits h, hT) ----------------
__global__ __launch_bounds__(256) void k_prep(
    const float* __restrict__ x, unsigned short* __restrict__ xh,
    unsigned short* __restrict__ xT) {
  __shared__ unsigned short tile[32][33];
  int b = blockIdx.z;
  int s0 = blockIdx.x * 32;
  int d0 = blockIdx.y * 32;
  int t = threadIdx.x;
  int r = t >> 3;
  int c4 = (t & 7) * 4;

  long src = (long)(b * SEQ + s0 + r) * DIM + d0 + c4;
  float4 v = *(const float4*)(x + src);
  float vv[4] = {v.x, v.y, v.z, v.w};
  unsigned short hu[4];
#pragma unroll
  for (int j = 0; j < 4; ++j) {
    hu[j] = f2h(vv[j]);
    tile[r][c4 + j] = hu[j];
  }
  *(ushort4*)(xh + src) = make_ushort4(hu[0], hu[1], hu[2], hu[3]);
  __syncthreads();
  unsigned short tv[4];
#pragma unroll
  for (int j = 0; j < 4; ++j) tv[j] = tile[c4 + j][r];
  long dst = (long)(b * DIM + d0 + r) * SEQ + s0 + c4;
  *(ushort4*)(xT + dst) = make_ushort4(tv[0], tv[1], tv[2], tv[3]);
}

// shared compute macro (R5-exact structure, f16 MFMA) — used by k_scores
#define COMPUTE_TILE(ARR_A, ARR_B, BUF)                                     \
  {                                                                         \
    half8 af[4], bg[4];                                                     \
    _Pragma("unroll") for (int m = 0; m < 4; ++m) {                         \
      int R = wr * 64 + m * 16 + l15;                                       \
      af[m] = *(const half8*)&ARR_A[BUF][R * BK + ((lhi ^ ((R >> 1) & 3)) * 8)]; \
    }                                                                       \
    _Pragma("unroll") for (int n = 0; n < 4; ++n) {                         \
      int R = wc * 64 + n * 16 + l15;                                       \
      bg[n] = *(const half8*)&ARR_B[BUF][R * BK + ((lhi ^ ((R >> 1) & 3)) * 8)]; \
    }                                                                       \
    _Pragma("unroll") for (int m = 0; m < 4; ++m)                           \
      _Pragma("unroll") for (int n = 0; n < 4; ++n)                         \
        acc[m][n] = __builtin_amdgcn_mfma_f32_16x16x32_f16(af[m], bg[n], acc[m][n], 0, 0, 0); \
  }

// ---------------- K2: scores GEMM (128^2, single-pass h h^T, d3) ----------------
#define NT_SC 32
__global__ __launch_bounds__(256) void k_scores(
    const unsigned short* __restrict__ xh, unsigned short* __restrict__ S) {
  __shared__ unsigned short As[3][128 * BK];
  __shared__ unsigned short Bs[3][128 * BK];
  int p = blockIdx.x + 136 * blockIdx.z;   // 0..1087
  int b = p & 7;                            // one batch per XCD (T1)
  int t = p >> 3;                           // tri-index 0..135
  int bm = 0, rem = 16;
  while (t >= rem) { t -= rem; ++bm; --rem; }
  int bn = bm + t;
  int m0 = bm * 128;
  int n0 = bn * 128;
  const unsigned short* xh_b = xh + (long)b * SEQ * DIM;
  unsigned short* S_b = S + (long)b * SEQ * SEQ;

  int tid = threadIdx.x;
  int w = tid >> 6, lane = tid & 63;
  int wr = w >> 1, wc = w & 1;
  int l15 = lane & 15, lhi = lane >> 4;

  int cbase0 = w * 64, cbase1 = 256 + w * 64;
  int c0 = cbase0 + lane, c1 = cbase1 + lane;
  int row0 = c0 >> 2, row1 = c1 >> 2;
  long aoff0 = (long)(m0 + row0) * DIM + ((c0 & 3) ^ ((row0 >> 1) & 3)) * 8;
  long aoff1 = (long)(m0 + row1) * DIM + ((c1 & 3) ^ ((row1 >> 1) & 3)) * 8;
  long boff0 = (long)(n0 + row0) * DIM + ((c0 & 3) ^ ((row0 >> 1) & 3)) * 8;
  long boff1 = (long)(n0 + row1) * DIM + ((c1 & 3) ^ ((row1 >> 1) & 3)) * 8;

#define STAGE_SC(KT, BUF)                                                   \
  {                                                                         \
    int kk_ = (KT) * BK;                                                    \
    load16(xh_b + aoff0 + kk_, &As[BUF][cbase0 * 8]);                       \
    load16(xh_b + aoff1 + kk_, &As[BUF][cbase1 * 8]);                       \
    load16(xh_b + boff0 + kk_, &Bs[BUF][cbase0 * 8]);                       \
    load16(xh_b + boff1 + kk_, &Bs[BUF][cbase1 * 8]);                       \
  }

  f32x4 acc[4][4];
#pragma unroll
  for (int m = 0; m < 4; ++m)
#pragma unroll
    for (int n = 0; n < 4; ++n)
#pragma unroll
      for (int j = 0; j < 4; ++j) acc[m][n][j] = 0.0f;

  STAGE_SC(0, 0);
  STAGE_SC(1, 1);
  STAGE_SC(2, 2);
  int cur = 0;
  for (int kt = 0; kt < NT_SC - 2; ++kt) {
    asm volatile("s_waitcnt vmcnt(8)" ::: "memory");
    __builtin_amdgcn_s_barrier();
    __builtin_amdgcn_sched_barrier(0);
    COMPUTE_TILE(As, Bs, cur);
    __builtin_amdgcn_sched_barrier(0);
    __builtin_amdgcn_s_barrier();
    if (kt + 3 < NT_SC) STAGE_SC(kt + 3, cur);
    cur = (cur == 2) ? 0 : cur + 1;
  }
  asm volatile("s_waitcnt vmcnt(4)" ::: "memory");
  __builtin_amdgcn_s_barrier();
  COMPUTE_TILE(As, Bs, (NT_SC - 2) % 3);
  asm volatile("s_waitcnt vmcnt(0)" ::: "memory");
  __builtin_amdgcn_s_barrier();
  COMPUTE_TILE(As, Bs, (NT_SC - 1) % 3);

  // normal-orientation write (scalar fp16), S = acc
#pragma unroll
  for (int m = 0; m < 4; ++m)
#pragma unroll
    for (int n = 0; n < 4; ++n)
#pragma unroll
      for (int j = 0; j < 4; ++j) {
        int r = m0 + wr * 64 + m * 16 + lhi * 4 + j;
        int c = n0 + wc * 64 + n * 16 + l15;
        S_b[(long)r * SEQ + c] = f2h(acc[m][n][j]);
      }
  // transposed write for off-diagonal blocks
  if (bm != bn) {
#pragma unroll
    for (int m = 0; m < 4; ++m)
#pragma unroll
      for (int n = 0; n < 4; ++n) {
        int r0 = m0 + wr * 64 + m * 16 + lhi * 4;
        int c = n0 + wc * 64 + n * 16 + l15;
        *(ushort4*)&S_b[(long)c * SEQ + r0] = make_ushort4(
            f2h(acc[m][n][0]), f2h(acc[m][n][1]),
            f2h(acc[m][n][2]), f2h(acc[m][n][3]));
      }
  }
}

// ---------------- K3: masked softmax (fp16 in, fp16 out), wave per row ----------------
__global__ __launch_bounds__(256) void k_softmax(
    const unsigned short* __restrict__ S, const int* __restrict__ mask,
    unsigned short* __restrict__ P) {
  int w = threadIdx.x >> 6, lane = threadIdx.x & 63;
  long row = (long)blockIdx.x * 4 + w;
  int b = (int)(row >> 11);
  const unsigned short* Sp = S + row * SEQ;
  const int* mp = mask + b * SEQ;
  unsigned short* Pp = P + row * SEQ;

  float sv[32];
  float mx = -__builtin_inff();
#pragma unroll
  for (int ci = 0; ci < 4; ++ci) {
    int col = ci * 512 + lane * 8;
    ushort8 v = *(const ushort8*)(Sp + col);
    int4 ma = *(const int4*)(mp + col);
    int4 mb = *(const int4*)(mp + col + 4);
    int mk[8] = {ma.x, ma.y, ma.z, ma.w, mb.x, mb.y, mb.z, mb.w};
#pragma unroll
    for (int j = 0; j < 8; ++j) {
      float s = mk[j] ? h2f(v[j]) : -__builtin_inff();
      sv[ci * 8 + j] = s;
      mx = fmaxf(mx, s);
    }
  }
#pragma unroll
  for (int off = 32; off; off >>= 1) mx = fmaxf(mx, __shfl_xor(mx, off));
  float pv[32];
  float sum = 0.0f;
#pragma unroll
  for (int i = 0; i < 32; ++i) {
    pv[i] = expf(sv[i] - mx);
    sum += pv[i];
  }
#pragma unroll
  for (int off = 32; off; off >>= 1) sum += __shfl_xor(sum, off);
  float inv = 1.0f / sum;
#pragma unroll
  for (int ci = 0; ci < 4; ++ci) {
    int col = ci * 512 + lane * 8;
    ushort8 o;
#pragma unroll
    for (int j = 0; j < 8; ++j) o[j] = f2h(pv[ci * 8 + j] * inv);
    *(ushort8*)(Pp + col) = o;
  }
}

// ---------------- K4: context GEMM 256^2 BK=64, 2 phases/tile ----------------
#define NT_CTX 32
__global__ __launch_bounds__(512, 2) void k_context(
    const unsigned short* __restrict__ P, const unsigned short* __restrict__ xT,
    const float* __restrict__ x, float* __restrict__ out) {
  __shared__ unsigned short As[2 * 16384];  // 64 KB
  __shared__ unsigned short Bs[2 * 16384];  // 64 KB
  int p = blockIdx.x;            // 0..255
  int b = p & 7;                 // one batch per XCD (T1)
  int q = p >> 3;                // 0..31
  int n0 = (q & 3) * 256;        // d cols
  int m0 = (q >> 2) * 256;       // q rows
  const unsigned short* A_b = P + (long)b * SEQ * SEQ;
  const unsigned short* B_b = xT + (long)b * DIM * SEQ;

  int tid = threadIdx.x;
  int w = tid >> 6, lane = tid & 63;
  int wr = w >> 2, wc = w & 3;          // 2M x 4N waves; per-wave 128x64
  int l15 = lane & 15, lhi = lane >> 4;

  int c0 = w * 128 + lane, c1 = w * 128 + 64 + lane;
  int R0 = c0 >> 2, R1 = c1 >> 2;
  int sw0 = ((c0 & 3) ^ ((R0 >> 1) & 3)) * 8;
  int sw1 = ((c1 & 3) ^ ((R1 >> 1) & 3)) * 8;
  const unsigned short* PA0 = A_b + (long)(m0 + R0) * SEQ + sw0;
  const unsigned short* PA1 = A_b + (long)(m0 + R1) * SEQ + sw1;
  const unsigned short* PB0 = B_b + (long)(n0 + R0) * SEQ + sw0;
  const unsigned short* PB1 = B_b + (long)(n0 + R1) * SEQ + sw1;
  int ldg0 = (w * 128) * 8;
  int ldg1 = (w * 128 + 64) * 8;

#define STG_A(KT, KK, BUF)                                              \
  {                                                                     \
    load16(PA0 + (KT) * 64 + (KK) * 32, &As[(BUF)*16384 + (KK)*8192 + ldg0]); \
    load16(PA1 + (KT) * 64 + (KK) * 32, &As[(BUF)*16384 + (KK)*8192 + ldg1]); \
  }
#define STG_B(KT, KK, BUF)                                              \
  {                                                                     \
    load16(PB0 + (KT) * 64 + (KK) * 32, &Bs[(BUF)*16384 + (KK)*8192 + ldg0]); \
    load16(PB1 + (KT) * 64 + (KK) * 32, &Bs[(BUF)*16384 + (KK)*8192 + ldg1]); \
  }

  int swr = (lhi ^ ((l15 >> 1) & 3)) * 8;
  int arow = (wr * 128 + l15) * 32;
  int brow = (wc * 64 + l15) * 32;

  // one kk-half phase: read 12 frags, stage 4 loads, PH discipline, 32 MFMA
#define PHASE_CTX(BUF, KK, DO_STG_A, DO_STG_B, STKT, STKK, STBUF)             \
  {                                                                           \
    half8 af[8], bg[4];                                                       \
    _Pragma("unroll") for (int n = 0; n < 4; ++n)                             \
        bg[n] = *(const half8*)&Bs[(BUF)*16384 + (KK)*8192 + brow + n * 512 + swr]; \
    _Pragma("unroll") for (int m = 0; m < 8; ++m)                             \
        af[m] = *(const half8*)&As[(BUF)*16384 + (KK)*8192 + arow + m * 512 + swr]; \
    if (DO_STG_A) STG_A(STKT, STKK, STBUF);                                   \
    if (DO_STG_B) STG_B(STKT, STKK, STBUF);                                   \
    __builtin_amdgcn_s_barrier();                                             \
    asm volatile("s_waitcnt lgkmcnt(0)" ::: "memory");                        \
    __builtin_amdgcn_sched_barrier(0);                                        \
    __builtin_amdgcn_s_setprio(1);                                            \
    _Pragma("unroll") for (int m = 0; m < 8; ++m)                             \
      _Pragma("unroll") for (int n = 0; n < 4; ++n)                           \
        acc[m][n] = __builtin_amdgcn_mfma_f32_16x16x32_f16(                   \
            bg[n], af[m], acc[m][n], 0, 0, 0);                                \
    __builtin_amdgcn_s_setprio(0);                                            \
    __builtin_amdgcn_sched_barrier(0);                                        \
  }

  f32x4 acc[8][4];
#pragma unroll
  for (int m = 0; m < 8; ++m)
#pragma unroll
    for (int n = 0; n < 4; ++n)
#pragma unroll
      for (int j = 0; j < 4; ++j) acc[m][n][j] = 0.0f;

  // prologue: kt0 full (8 loads) + kt1 kk0 (4 loads); drain kt0 -> vmcnt(4)
  STG_A(0, 0, 0); STG_B(0, 0, 0);
  STG_A(0, 1, 0); STG_B(0, 1, 0);
  STG_A(1, 0, 1); STG_B(1, 0, 1);
  asm volatile("s_waitcnt vmcnt(4)" ::: "memory");
  __builtin_amdgcn_s_barrier();

  for (int kt = 0; kt < NT_CTX; ++kt) {
    int c = kt & 1, o = c ^ 1;
    int haveN1 = (kt + 1 < NT_CTX), haveN2 = (kt + 2 < NT_CTX);
    // phase A: compute kk0 of c; stage kt+1-kk1 -> o
    PHASE_CTX(c, 0, haveN1, haveN1, kt + 1, 1, o);
    __builtin_amdgcn_s_barrier();   // all waves done reading c-kk0
    // phase B: compute kk1 of c; stage kt+2-kk0 -> c (region just released)
    PHASE_CTX(c, 1, haveN2, haveN2, kt + 2, 0, c);
    if (kt < NT_CTX - 2) {
      asm volatile("s_waitcnt vmcnt(4)" ::: "memory");
    } else if (kt == NT_CTX - 2) {
      asm volatile("s_waitcnt vmcnt(0)" ::: "memory");
    }
    __builtin_amdgcn_s_barrier();
  }

  // epilogue: swapped-operand C layout -> thread holds 4 consecutive d (f32x4)
  // nontemporal: output is streamed once, never re-read
  const float* x_b = x + (long)b * SEQ * DIM;
  float* out_b = out + (long)b * SEQ * (5 * DIM);
#pragma unroll
  for (int m = 0; m < 8; ++m)
#pragma unroll
    for (int n = 0; n < 4; ++n) {
      int qi = m0 + wr * 128 + m * 16 + l15;      // col index = q
      int d = n0 + wc * 64 + n * 16 + lhi * 4;    // row index = d (4 consec)
      f32x4 c4 = acc[m][n];
      f32x4 xv = *(const f32x4*)&x_b[(long)qi * DIM + d];
      long base = (long)qi * (5 * DIM) + d;
      __builtin_nontemporal_store(xv,       (f32x4*)&out_b[base]);
      __builtin_nontemporal_store(c4,       (f32x4*)&out_b[base + DIM]);
      __builtin_nontemporal_store(xv + c4,  (f32x4*)&out_b[base + 2 * DIM]);
      __builtin_nontemporal_store(xv - c4,  (f32x4*)&out_b[base + 3 * DIM]);
      __builtin_nontemporal_store(xv * c4,  (f32x4*)&out_b[base + 4 * DIM]);
    }
}

extern "C" void kernel_launch(void* const* d_in, const int* in_sizes, int n_in,
                              void* d_out, int out_size, void* d_ws, size_t ws_size,
                              hipStream_t stream) {
  const float* x = (const float*)d_in[0];
  const int* mask = (const int*)d_in[1];
  float* out = (float*)d_out;
  char* ws = (char*)d_ws;

  const size_t HB = (size_t)NBATCH * SEQ * DIM * 2;
  unsigned short* xh = (unsigned short*)ws;
  unsigned short* xT = (unsigned short*)(ws + HB);
  unsigned short* P = (unsigned short*)(ws + 2 * HB);
  const size_t PB = (size_t)NBATCH * SEQ * SEQ * 2;
  const size_t SB = (size_t)NBATCH * SEQ * SEQ * 2;   // S fp16
  unsigned short* S;
  if (ws_size >= 2 * HB + PB + SB) {
    S = (unsigned short*)(ws + 2 * HB + PB);
  } else {
    S = (unsigned short*)d_out;  // S dead before K4 writes out
  }

  k_prep<<<dim3(SEQ / 32, DIM / 32, NBATCH), 256, 0, stream>>>(x, xh, xT);
  k_scores<<<dim3(136, 1, NBATCH), 256, 0, stream>>>(xh, S);
  k_softmax<<<NBATCH * SEQ / 4, 256, 0, stream>>>(S, mask, P);
  k_context<<<dim3(256, 1, 1), 512, 0, stream>>>(P, xT, x, out);
}